// Round 7
// baseline (692.810 us; speedup 1.0000x reference)
//
#include <hip/hip_runtime.h>
#include <math.h>

#define N_ROWS 32768
#define KCB    8192
#define DIM    512
#define BETA   0.25f
#define MARGIN 2e-3f
#define FLAG_SLACK 1e-4f
#define CAND_CAP 256
#define NITER  4

typedef __attribute__((ext_vector_type(4))) float  f32x4;

__device__ __forceinline__ unsigned short f2h(float x) {
    _Float16 h = (_Float16)x;
    return *(unsigned short*)&h;
}
__device__ __forceinline__ float h2f(unsigned short u) {
    _Float16 h = *(_Float16*)&u;
    return (float)h;
}

// ---------------------------------------------------------------------------
// Kernel 1 (fused pre-pass). Blocks [0,5120): ||x||^2 / ||e||^2 with numpy's
// exact pairwise tree (sequential-i per lane + commutative butterfly).
// Blocks [5120,15360): fp32 -> fp8 e4m3 convert (emb pre-scaled by 2^13).
// Also zeroes the correct-counter.
// ---------------------------------------------------------------------------
#define SQ_BLOCKS ((N_ROWS + KCB) / 8)
__global__ __launch_bounds__(256) void pre_kernel(
        const float* __restrict__ lat, const float* __restrict__ emb,
        float* __restrict__ row_sq, float* __restrict__ emb_sq,
        unsigned char* __restrict__ latq, unsigned char* __restrict__ embq,
        int* __restrict__ counter) {
    if (blockIdx.x < SQ_BLOCKS) {
#pragma clang fp contract(off)
        if (blockIdx.x == 0 && threadIdx.x == 0) *counter = 0;
        const int w    = threadIdx.x >> 6;
        const int lane = threadIdx.x & 63;
        const int half = lane >> 5;
        const int L    = lane & 31;
        const int b    = L >> 3, j = L & 7;
        const int row  = blockIdx.x * 8 + w * 2 + half;
        const float* p = (row < N_ROWS) ? (lat + (size_t)row * DIM)
                                        : (emb + (size_t)(row - N_ROWS) * DIM);
        const float* q = p + 128 * b + j;
        float a0 = q[0];
        float r  = a0 * a0;
        for (int i = 1; i < 16; ++i) {
            float a = q[8 * i];
            float s = a * a;
            r = r + s;
        }
        r = r + __shfl_xor(r, 1);
        r = r + __shfl_xor(r, 2);
        r = r + __shfl_xor(r, 4);
        r = r + __shfl_xor(r, 8);
        r = r + __shfl_xor(r, 16);
        if (L == 0) {
            if (row < N_ROWS) row_sq[row] = r;
            else              emb_sq[row - N_ROWS] = r;
        }
    } else {
        const size_t NL8 = (size_t)N_ROWS * DIM / 8;
        const size_t NE8 = (size_t)KCB * DIM / 8;
        size_t g = (size_t)(blockIdx.x - SQ_BLOCKS) * 256 + threadIdx.x;
        const float* src; unsigned char* dst; size_t i; float sc;
        if (g < NL8)            { src = lat; dst = latq; i = g;       sc = 1.0f; }
        else if (g < NL8 + NE8) { src = emb; dst = embq; i = g - NL8; sc = 8192.0f; }
        else return;
        float4 v0 = ((const float4*)src)[2 * i];
        float4 v1 = ((const float4*)src)[2 * i + 1];
        int lo = __builtin_amdgcn_cvt_pk_fp8_f32(v0.x * sc, v0.y * sc, 0,  false);
        lo     = __builtin_amdgcn_cvt_pk_fp8_f32(v0.z * sc, v0.w * sc, lo, true);
        int hi = __builtin_amdgcn_cvt_pk_fp8_f32(v1.x * sc, v1.y * sc, 0,  false);
        hi     = __builtin_amdgcn_cvt_pk_fp8_f32(v1.z * sc, v1.w * sc, hi, true);
        ((int2*)dst)[i] = make_int2(lo, hi);
    }
}

// ---------------------------------------------------------------------------
// Kernel 2: fp8 MFMA GEMM (transposed: D[code][latrow]), BK=128 staging
// (48 KB LDS, 2 blocks/CU, half the barriers of BK=64). Epilogue packs
// {bitmap[31:16], fp16(groupmin - sx)[15:0]} per 16-code group, uint4 store.
// ---------------------------------------------------------------------------
__device__ __forceinline__ void load16_to_lds(const void* g, void* l) {
    __builtin_amdgcn_global_load_lds(
        (const __attribute__((address_space(1))) unsigned int*)g,
        (__attribute__((address_space(3))) unsigned int*)l, 16, 0, 0);
}

__global__ __launch_bounds__(256, 2) void gemm_kernel(
        const unsigned char* __restrict__ latq,
        const unsigned char* __restrict__ embq,
        const float* __restrict__ row_sq,
        const float* __restrict__ emb_sq,
        unsigned int* __restrict__ packed) {
    __shared__ unsigned char Ac[8 * 128 * 16];   // codes [p][128][16B], 16 KB
    __shared__ unsigned char Br[8 * 256 * 16];   // rows  [p][256][16B], 32 KB

    const int tid   = threadIdx.x;
    const int w     = tid >> 6;
    const int lane  = tid & 63;
    const int q     = lane >> 4;
    const int m16   = lane & 15;
    const int row0  = blockIdx.x * 256;
    const int nbase = blockIdx.y * (NITER * 128);
    const int wc    = 64 * (w >> 1);
    const int rbase = 128 * (w & 1);

    float sxv[8];
#pragma unroll
    for (int c = 0; c < 8; ++c)
        sxv[c] = row_sq[row0 + rbase + 16 * c + m16];

    const float inv = 1.0f / 4096.0f;   // undo 2^13 emb scale on 2*dot

    for (int ni = 0; ni < NITER; ++ni) {
        const int n0 = nbase + ni * 128;
        float sev[4][4];
#pragma unroll
        for (int r = 0; r < 4; ++r)
#pragma unroll
            for (int reg = 0; reg < 4; ++reg)
                sev[r][reg] = emb_sq[n0 + wc + 16 * r + 4 * q + reg];

        f32x4 acc[4][8];
#pragma unroll
        for (int r = 0; r < 4; ++r)
#pragma unroll
            for (int c = 0; c < 8; ++c) acc[r][c] = (f32x4){0.f, 0.f, 0.f, 0.f};

        for (int k0 = 0; k0 < DIM; k0 += 128) {
            // 48 chunks of 1 KB: 16 code-chunks + 32 row-chunks, 12/wave
#pragma unroll
            for (int i = 0; i < 12; ++i) {
                int cid = w * 12 + i;
                if (cid < 16) {
                    int p = cid >> 1, h = cid & 1;
                    const unsigned char* g = embq +
                        (size_t)(n0 + h * 64 + lane) * DIM + k0 + p * 16;
                    load16_to_lds(g, &Ac[(p * 128 + h * 64) * 16]);
                } else {
                    int c2 = cid - 16, p = c2 >> 2, h = c2 & 3;
                    const unsigned char* g = latq +
                        (size_t)(row0 + h * 64 + lane) * DIM + k0 + p * 16;
                    load16_to_lds(g, &Br[(p * 256 + h * 64) * 16]);
                }
            }
            __syncthreads();
#pragma unroll
            for (int kk = 0; kk < 4; ++kk) {
                long a[4], b[8];
                const int p  = 2 * kk + (q >> 1);
                const int hf = (q & 1) * 8;
#pragma unroll
                for (int r = 0; r < 4; ++r)
                    a[r] = *(const long*)&Ac[(p * 128 + wc + 16 * r + m16) * 16 + hf];
#pragma unroll
                for (int c = 0; c < 8; ++c)
                    b[c] = *(const long*)&Br[(p * 256 + rbase + 16 * c + m16) * 16 + hf];
#pragma unroll
                for (int r = 0; r < 4; ++r)
#pragma unroll
                    for (int c = 0; c < 8; ++c)
                        acc[r][c] = __builtin_amdgcn_mfma_f32_16x16x32_fp8_fp8(
                            a[r], b[c], acc[r][c], 0, 0, 0);
            }
            __syncthreads();
        }

        // epilogue: s = (sx+se) - 2^-12*dotq ; per-16-code-group min + bitmap
#pragma unroll
        for (int c = 0; c < 8; ++c) {
            unsigned pk[4];
#pragma unroll
            for (int r = 0; r < 4; ++r) {
                float s0 = (sxv[c] + sev[r][0]) - acc[r][c][0] * inv;
                float s1 = (sxv[c] + sev[r][1]) - acc[r][c][1] * inv;
                float s2 = (sxv[c] + sev[r][2]) - acc[r][c][2] * inv;
                float s3 = (sxv[c] + sev[r][3]) - acc[r][c][3] * inv;
                float mn = fminf(fminf(s0, s1), fminf(s2, s3));
                mn = fminf(mn, __shfl_xor(mn, 16));
                mn = fminf(mn, __shfl_xor(mn, 32));
                float t = mn + MARGIN;
                unsigned nib = (s0 <= t ? 1u : 0u) | (s1 <= t ? 2u : 0u)
                             | (s2 <= t ? 4u : 0u) | (s3 <= t ? 8u : 0u);
                nib <<= (4 * q);
                nib |= (unsigned)__shfl_xor((int)nib, 16);
                nib |= (unsigned)__shfl_xor((int)nib, 32);
                // rel = mn - sx is exact (Sterbenz); fp16 RNE, bitmap in hi16
                pk[r] = ((unsigned)f2h(mn - sxv[c])) | (nib << 16);
            }
            if (lane < 16) {
                int grow = row0 + rbase + 16 * c + m16;
                int base = (n0 + wc) >> 4;
                *(uint4*)&packed[(size_t)grow * 512 + base] =
                    make_uint4(pk[0], pk[1], pk[2], pk[3]);
            }
        }
    }
}

// ---------------------------------------------------------------------------
// Kernel 3 (fused): global min of fp16 group mins -> flagged groups ->
// candidate codes from bitmaps -> exact fp32 rescore (R1's bit-identical
// sequential-fmaf chain) -> quantized write, vq_loss, inds, correct count.
// ---------------------------------------------------------------------------
__global__ __launch_bounds__(256) void argmin_out_kernel(
        const float* __restrict__ lat, const float* __restrict__ emb,
        const float* __restrict__ row_sq, const float* __restrict__ emb_sq,
        const unsigned int* __restrict__ packed,
        const int* __restrict__ gold,
        float* __restrict__ out, int* __restrict__ counter) {
    __shared__ float xs[4][DIM];
    __shared__ int   s_cnt[4];
    __shared__ int   s_list[4][CAND_CAP];
    const int w    = threadIdx.x >> 6;
    const int lane = threadIdx.x & 63;
    const int row  = blockIdx.x * 4 + w;

    {
        const float4* xp = (const float4*)(lat + (size_t)row * DIM);
        ((float4*)xs[w])[lane]      = xp[lane];
        ((float4*)xs[w])[lane + 64] = xp[lane + 64];
    }
    const float sx = row_sq[row];
    const float* xw = xs[w];

    unsigned u[8];
    {
        const uint4* tb = (const uint4*)(packed + (size_t)row * 512 + lane * 8);
        uint4 v0 = tb[0], v1 = tb[1];
        u[0] = v0.x; u[1] = v0.y; u[2] = v0.z; u[3] = v0.w;
        u[4] = v1.x; u[5] = v1.y; u[6] = v1.z; u[7] = v1.w;
    }
    float tm[8];
#pragma unroll
    for (int j = 0; j < 8; ++j) tm[j] = h2f((unsigned short)(u[j] & 0xFFFFu));
    float m = tm[0];
#pragma unroll
    for (int j = 1; j < 8; ++j) m = fminf(m, tm[j]);
#pragma unroll
    for (int off = 1; off < 64; off <<= 1)
        m = fminf(m, __shfl_xor(m, off));
    const float thresh = m + (MARGIN + FLAG_SLACK);

    if (lane == 0) s_cnt[w] = 0;
    __syncthreads();
#pragma unroll
    for (int j = 0; j < 8; ++j) {
        if (tm[j] <= thresh) {
            int g = lane * 8 + j;
            unsigned bm = u[j] >> 16;
            while (bm) {
                int b = __ffs(bm) - 1;
                bm &= bm - 1;
                int pos = atomicAdd(&s_cnt[w], 1);
                if (pos < CAND_CAP) s_list[w][pos] = g * 16 + b;
            }
        }
    }
    __syncthreads();
    const int cnt = min(s_cnt[w], CAND_CAP);

    float bd = INFINITY;
    int   bi = 0x7fffffff;
    for (int base = 0; base < cnt; base += 64) {
        int ci = base + lane;
        float dvl = INFINITY;
        int   cl  = 0x7fffffff;
        if (ci < cnt) {
            int code = s_list[w][ci];
            const float* ep = emb + (size_t)code * DIM;
            float acc = 0.0f;
            for (int d = 0; d < DIM; d += 8) {
                float ev[8], xv[8];
#pragma unroll
                for (int t = 0; t < 8; ++t) { ev[t] = ep[d + t]; xv[t] = xw[d + t]; }
#pragma unroll
                for (int t = 0; t < 8; ++t) acc = fmaf(xv[t], ev[t], acc);
            }
            float a = sx + emb_sq[code];
            dvl = a - 2.0f * acc;
            cl  = code;
        }
        if (dvl < bd || (dvl == bd && cl < bi)) { bd = dvl; bi = cl; }
    }
#pragma unroll
    for (int off = 1; off < 64; off <<= 1) {
        float od = __shfl_xor(bd, off);
        int   oi = __shfl_xor(bi, off);
        if (od < bd || (od == bd && oi < bi)) { bd = od; bi = oi; }
    }
    const int idx = bi;

    const float4* e4 = (const float4*)(emb + (size_t)idx * DIM);
    float4*       q4 = (float4*)(out + (size_t)row * DIM);
    q4[lane]      = e4[lane];
    q4[lane + 64] = e4[lane + 64];

    float r = 0.0f;
    if (lane < 32) {
        const int b = lane >> 3, j = lane & 7;
        const float* ep = emb + (size_t)idx * DIM + b * 128 + j;
        const float* xp = xw + b * 128 + j;
        for (int i = 0; i < 16; ++i) {
            float dq = ep[8 * i] - xp[8 * i];
            float s  = dq * dq;
            r = (i == 0) ? s : (r + s);
        }
    }
    for (int mm = 1; mm <= 16; mm <<= 1) {
        float o = __shfl_xor(r, mm);
        r = r + o;
    }
    if (lane == 0) {
        float mean = r * (1.0f / 512.0f);
        float v    = mean + 0.25f * mean;
        out[(size_t)N_ROWS * DIM + row]          = v;
        out[(size_t)N_ROWS * DIM + N_ROWS + row] = (float)idx;
        if (gold[row] == idx) atomicAdd(counter, 1);
    }
}

__global__ void tail_kernel(const int* __restrict__ counter,
                            float* __restrict__ out) {
    if (threadIdx.x == 0 && blockIdx.x == 0) {
        const size_t off = (size_t)N_ROWS * DIM + 2 * (size_t)N_ROWS;
        out[off]     = (float)(*counter);
        out[off + 1] = (float)N_ROWS;
    }
}

// ---------------------------------------------------------------------------
// Fallback path (tiny ws): R1 fp32 dist + separate sq/out kernels.
// ---------------------------------------------------------------------------
__global__ __launch_bounds__(256) void sq_kernel(
        const float* __restrict__ lat, const float* __restrict__ emb,
        float* __restrict__ row_sq, float* __restrict__ emb_sq) {
#pragma clang fp contract(off)
    const int w    = threadIdx.x >> 6;
    const int lane = threadIdx.x & 63;
    const int half = lane >> 5;
    const int L    = lane & 31;
    const int b    = L >> 3, j = L & 7;
    const int row  = blockIdx.x * 8 + w * 2 + half;
    if (row >= N_ROWS + KCB) return;
    const float* p = (row < N_ROWS) ? (lat + (size_t)row * DIM)
                                    : (emb + (size_t)(row - N_ROWS) * DIM);
    const float* q = p + 128 * b + j;
    float a0 = q[0];
    float r  = a0 * a0;
    for (int i = 1; i < 16; ++i) {
        float a = q[8 * i];
        float s = a * a;
        r = r + s;
    }
    r = r + __shfl_xor(r, 1);
    r = r + __shfl_xor(r, 2);
    r = r + __shfl_xor(r, 4);
    r = r + __shfl_xor(r, 8);
    r = r + __shfl_xor(r, 16);
    if (L == 0) {
        if (row < N_ROWS) row_sq[row] = r;
        else              emb_sq[row - N_ROWS] = r;
    }
}

#define BM 64
#define BK 128
#define BD 32
__global__ __launch_bounds__(256) void dist_kernel(
        const float* __restrict__ lat, const float* __restrict__ emb,
        const float* __restrict__ row_sq, const float* __restrict__ emb_sq,
        int* __restrict__ enc) {
    __shared__ float xsh[BD][BM];
    __shared__ float esh[BD][BK];
    const int tid  = threadIdx.x;
    const int trow = tid >> 4;
    const int tcol = tid & 15;
    const int row0 = blockIdx.x * BM;
    float bd[4]; int bi[4];
    for (int i = 0; i < 4; ++i) { bd[i] = INFINITY; bi[i] = 0; }
    float sx[4];
    for (int i = 0; i < 4; ++i) sx[i] = row_sq[row0 + 4 * trow + i];
    for (int kt = 0; kt < KCB; kt += BK) {
        float acc[4][8] = {};
        for (int d0 = 0; d0 < DIM; d0 += BD) {
            for (int f = tid; f < BM * BD / 4; f += 256) {
                int r = f >> 3, c4 = f & 7;
                float4 v = *(const float4*)(lat + (size_t)(row0 + r) * DIM + d0 + 4 * c4);
                xsh[4 * c4 + 0][r] = v.x; xsh[4 * c4 + 1][r] = v.y;
                xsh[4 * c4 + 2][r] = v.z; xsh[4 * c4 + 3][r] = v.w;
            }
            for (int f = tid; f < BK * BD / 4; f += 256) {
                int r = f >> 3, c4 = f & 7;
                float4 v = *(const float4*)(emb + (size_t)(kt + r) * DIM + d0 + 4 * c4);
                esh[4 * c4 + 0][r] = v.x; esh[4 * c4 + 1][r] = v.y;
                esh[4 * c4 + 2][r] = v.z; esh[4 * c4 + 3][r] = v.w;
            }
            __syncthreads();
            for (int dd = 0; dd < BD; ++dd) {
                float4 xv  = *(const float4*)&xsh[dd][4 * trow];
                float4 ev0 = *(const float4*)&esh[dd][8 * tcol];
                float4 ev1 = *(const float4*)&esh[dd][8 * tcol + 4];
                float xr[4] = { xv.x, xv.y, xv.z, xv.w };
                float ec[8] = { ev0.x, ev0.y, ev0.z, ev0.w, ev1.x, ev1.y, ev1.z, ev1.w };
                for (int r = 0; r < 4; ++r)
                    for (int c = 0; c < 8; ++c)
                        acc[r][c] = fmaf(xr[r], ec[c], acc[r][c]);
            }
            __syncthreads();
        }
        for (int c = 0; c < 8; ++c) {
            int   code = kt + 8 * tcol + c;
            float se   = emb_sq[code];
            for (int r = 0; r < 4; ++r) {
                float a  = sx[r] + se;
                float dv = a - 2.0f * acc[r][c];
                if (dv < bd[r]) { bd[r] = dv; bi[r] = code; }
            }
        }
    }
    for (int off = 1; off < 16; off <<= 1) {
        for (int r = 0; r < 4; ++r) {
            float od = __shfl_xor(bd[r], off);
            int   oi = __shfl_xor(bi[r], off);
            if (od < bd[r] || (od == bd[r] && oi < bi[r])) { bd[r] = od; bi[r] = oi; }
        }
    }
    if (tcol == 0)
        for (int r = 0; r < 4; ++r)
            enc[row0 + 4 * trow + r] = bi[r];
}

__global__ void out_kernel(const float* __restrict__ lat,
                           const float* __restrict__ emb,
                           const int* __restrict__ gold,
                           const int* __restrict__ enc,
                           float* __restrict__ out,
                           int* __restrict__ counter) {
#pragma clang fp contract(off)
    const int gid  = blockIdx.x * blockDim.x + threadIdx.x;
    const int row  = gid >> 6;
    const int lane = threadIdx.x & 63;
    if (row >= N_ROWS) return;
    const int idx = enc[row];
    const float4* e4 = (const float4*)(emb + (size_t)idx * DIM);
    float4*       q4 = (float4*)(out + (size_t)row * DIM);
    q4[lane]      = e4[lane];
    q4[lane + 64] = e4[lane + 64];
    float r = 0.0f;
    if (lane < 32) {
        const int b = lane >> 3, j = lane & 7;
        const float* ep = emb + (size_t)idx * DIM + b * 128 + j;
        const float* xp = lat + (size_t)row * DIM + b * 128 + j;
        for (int i = 0; i < 16; ++i) {
            float dq = ep[8 * i] - xp[8 * i];
            float s  = dq * dq;
            r = (i == 0) ? s : (r + s);
        }
    }
    for (int m = 1; m <= 16; m <<= 1) {
        float o = __shfl_xor(r, m);
        r = r + o;
    }
    if (lane == 0) {
        float mean = r * (1.0f / 512.0f);
        float v    = mean + 0.25f * mean;
        out[(size_t)N_ROWS * DIM + row]          = v;
        out[(size_t)N_ROWS * DIM + N_ROWS + row] = (float)idx;
        if (gold[row] == idx) atomicAdd(counter, 1);
    }
}

// ---------------------------------------------------------------------------
extern "C" void kernel_launch(void* const* d_in, const int* in_sizes, int n_in,
                              void* d_out, int out_size, void* d_ws, size_t ws_size,
                              hipStream_t stream) {
    (void)in_sizes; (void)n_in; (void)out_size;
    const int*   gold = (const int*)d_in[0];
    const float* lat  = (const float*)d_in[1];
    const float* emb  = (const float*)d_in[3];
    float* out = (float*)d_out;

    const size_t SZ_LATQ = (size_t)N_ROWS * DIM;         // 16 MB
    const size_t SZ_EMBQ = (size_t)KCB * DIM;            //  4 MB
    const size_t SZ_PK   = (size_t)N_ROWS * 512 * 4;     // 64 MB
    const size_t SZ_SMALL = (size_t)N_ROWS * 4 + (size_t)KCB * 4 + 256;
    const size_t NEEDED = SZ_LATQ + SZ_EMBQ + SZ_PK + SZ_SMALL;

    if (ws_size >= NEEDED) {
        unsigned char* w8 = (unsigned char*)d_ws;
        unsigned char* latq    = w8;
        unsigned char* embq    = w8 + SZ_LATQ;
        unsigned int*  packed  = (unsigned int*)(w8 + SZ_LATQ + SZ_EMBQ);
        float*         row_sq  = (float*)(w8 + SZ_LATQ + SZ_EMBQ + SZ_PK);
        float*         emb_sq  = row_sq + N_ROWS;
        int*           counter = (int*)(emb_sq + KCB);

        const int pre_blocks = SQ_BLOCKS + (N_ROWS + KCB) * (DIM / 8) / 256;
        pre_kernel<<<pre_blocks, 256, 0, stream>>>(
            lat, emb, row_sq, emb_sq, latq, embq, counter);
        dim3 ggrid(N_ROWS / 256, KCB / (NITER * 128));
        gemm_kernel<<<ggrid, 256, 0, stream>>>(latq, embq, row_sq, emb_sq, packed);
        argmin_out_kernel<<<N_ROWS / 4, 256, 0, stream>>>(
            lat, emb, row_sq, emb_sq, packed, gold, out, counter);
        tail_kernel<<<1, 64, 0, stream>>>(counter, out);
    } else {
        float* row_sq  = (float*)d_ws;
        float* emb_sq  = row_sq + N_ROWS;
        int*   enc     = (int*)(emb_sq + KCB);
        int*   counter = enc + N_ROWS;
        hipMemsetAsync(counter, 0, sizeof(int), stream);
        sq_kernel<<<(N_ROWS + KCB) / 8, 256, 0, stream>>>(lat, emb, row_sq, emb_sq);
        dist_kernel<<<N_ROWS / BM, 256, 0, stream>>>(lat, emb, row_sq, emb_sq, enc);
        out_kernel<<<N_ROWS / 4, 256, 0, stream>>>(lat, emb, gold, enc, out, counter);
        tail_kernel<<<1, 64, 0, stream>>>(counter, out);
    }
}

// Round 8
// 644.602 us; speedup vs baseline: 1.0748x; 1.0748x over previous
//
#include <hip/hip_runtime.h>
#include <math.h>

#define N_ROWS 32768
#define KCB    8192
#define DIM    512
#define BETA   0.25f
#define MARGIN 2e-3f
#define FLAG_SLACK 1e-4f
#define CAND_CAP 256

typedef __attribute__((ext_vector_type(4))) float  f32x4;

__device__ __forceinline__ unsigned short f2h(float x) {
    _Float16 h = (_Float16)x;
    return *(unsigned short*)&h;
}
__device__ __forceinline__ float h2f(unsigned short u) {
    _Float16 h = *(_Float16*)&u;
    return (float)h;
}

// ---------------------------------------------------------------------------
// Kernel 1 (fused pre-pass): sq (numpy-exact pairwise tree) + fp8 convert.
// ---------------------------------------------------------------------------
#define SQ_BLOCKS ((N_ROWS + KCB) / 8)
__global__ __launch_bounds__(256) void pre_kernel(
        const float* __restrict__ lat, const float* __restrict__ emb,
        float* __restrict__ row_sq, float* __restrict__ emb_sq,
        unsigned char* __restrict__ latq, unsigned char* __restrict__ embq,
        int* __restrict__ counter) {
    if (blockIdx.x < SQ_BLOCKS) {
#pragma clang fp contract(off)
        if (blockIdx.x == 0 && threadIdx.x == 0) *counter = 0;
        const int w    = threadIdx.x >> 6;
        const int lane = threadIdx.x & 63;
        const int half = lane >> 5;
        const int L    = lane & 31;
        const int b    = L >> 3, j = L & 7;
        const int row  = blockIdx.x * 8 + w * 2 + half;
        const float* p = (row < N_ROWS) ? (lat + (size_t)row * DIM)
                                        : (emb + (size_t)(row - N_ROWS) * DIM);
        const float* q = p + 128 * b + j;
        float a0 = q[0];
        float r  = a0 * a0;
        for (int i = 1; i < 16; ++i) {
            float a = q[8 * i];
            float s = a * a;
            r = r + s;
        }
        r = r + __shfl_xor(r, 1);
        r = r + __shfl_xor(r, 2);
        r = r + __shfl_xor(r, 4);
        r = r + __shfl_xor(r, 8);
        r = r + __shfl_xor(r, 16);
        if (L == 0) {
            if (row < N_ROWS) row_sq[row] = r;
            else              emb_sq[row - N_ROWS] = r;
        }
    } else {
        const size_t NL8 = (size_t)N_ROWS * DIM / 8;
        const size_t NE8 = (size_t)KCB * DIM / 8;
        size_t g = (size_t)(blockIdx.x - SQ_BLOCKS) * 256 + threadIdx.x;
        const float* src; unsigned char* dst; size_t i; float sc;
        if (g < NL8)            { src = lat; dst = latq; i = g;       sc = 1.0f; }
        else if (g < NL8 + NE8) { src = emb; dst = embq; i = g - NL8; sc = 8192.0f; }
        else return;
        float4 v0 = ((const float4*)src)[2 * i];
        float4 v1 = ((const float4*)src)[2 * i + 1];
        int lo = __builtin_amdgcn_cvt_pk_fp8_f32(v0.x * sc, v0.y * sc, 0,  false);
        lo     = __builtin_amdgcn_cvt_pk_fp8_f32(v0.z * sc, v0.w * sc, lo, true);
        int hi = __builtin_amdgcn_cvt_pk_fp8_f32(v1.x * sc, v1.y * sc, 0,  false);
        hi     = __builtin_amdgcn_cvt_pk_fp8_f32(v1.z * sc, v1.w * sc, hi, true);
        ((int2*)dst)[i] = make_int2(lo, hi);
    }
}

// ---------------------------------------------------------------------------
// Kernel 2: fp8 MFMA GEMM (transposed: D[code][latrow]), m97/m145-style
// 128x128 tile: 4 waves (2x2) of 64 codes x 64 rows, acc = 64 AGPRs,
// BK=64 staging (16 KB LDS), ~3 blocks/CU. Epilogue is sx-free: packs
// {bitmap[31:16], fp16(min(se - 2*dot))[15:0]} per 16-code group.
// ---------------------------------------------------------------------------
__device__ __forceinline__ void load16_to_lds(const void* g, void* l) {
    __builtin_amdgcn_global_load_lds(
        (const __attribute__((address_space(1))) unsigned int*)g,
        (__attribute__((address_space(3))) unsigned int*)l, 16, 0, 0);
}

__global__ __launch_bounds__(256, 3) void gemm_kernel(
        const unsigned char* __restrict__ latq,
        const unsigned char* __restrict__ embq,
        const float* __restrict__ emb_sq,
        unsigned int* __restrict__ packed) {
    __shared__ unsigned char Ac[4 * 128 * 16];   // codes [p][128][16B], 8 KB
    __shared__ unsigned char Br[4 * 128 * 16];   // rows  [p][128][16B], 8 KB

    const int tid   = threadIdx.x;
    const int w     = tid >> 6;
    const int lane  = tid & 63;
    const int q     = lane >> 4;
    const int m16   = lane & 15;
    const int row0  = blockIdx.x * 128;
    const int code0 = blockIdx.y * 128;
    const int wc    = 64 * (w >> 1);
    const int rbase = 64 * (w & 1);

    float sev[4][4];
#pragma unroll
    for (int r = 0; r < 4; ++r)
#pragma unroll
        for (int reg = 0; reg < 4; ++reg)
            sev[r][reg] = emb_sq[code0 + wc + 16 * r + 4 * q + reg];

    f32x4 acc[4][4];
#pragma unroll
    for (int r = 0; r < 4; ++r)
#pragma unroll
        for (int c = 0; c < 4; ++c) acc[r][c] = (f32x4){0.f, 0.f, 0.f, 0.f};

    for (int k0 = 0; k0 < DIM; k0 += 64) {
        // 16 chunks of 1 KB: 8 code-chunks + 8 row-chunks, 4 per wave
#pragma unroll
        for (int i = 0; i < 4; ++i) {
            int cid = w * 4 + i;
            if (cid < 8) {
                int p = cid >> 1, h = cid & 1;
                const unsigned char* g = embq +
                    (size_t)(code0 + h * 64 + lane) * DIM + k0 + p * 16;
                load16_to_lds(g, &Ac[(p * 128 + h * 64) * 16]);
            } else {
                int c2 = cid - 8, p = c2 >> 1, h = c2 & 1;
                const unsigned char* g = latq +
                    (size_t)(row0 + h * 64 + lane) * DIM + k0 + p * 16;
                load16_to_lds(g, &Br[(p * 128 + h * 64) * 16]);
            }
        }
        __syncthreads();
#pragma unroll
        for (int kk = 0; kk < 2; ++kk) {
            long a[4], b[4];
            const int p  = 2 * kk + (q >> 1);
            const int hf = (q & 1) * 8;
#pragma unroll
            for (int r = 0; r < 4; ++r)
                a[r] = *(const long*)&Ac[(p * 128 + wc + 16 * r + m16) * 16 + hf];
#pragma unroll
            for (int c = 0; c < 4; ++c)
                b[c] = *(const long*)&Br[(p * 128 + rbase + 16 * c + m16) * 16 + hf];
#pragma unroll
            for (int r = 0; r < 4; ++r)
#pragma unroll
                for (int c = 0; c < 4; ++c)
                    acc[r][c] = __builtin_amdgcn_mfma_f32_16x16x32_fp8_fp8(
                        a[r], b[c], acc[r][c], 0, 0, 0);
        }
        __syncthreads();
    }

    // epilogue (sx-free): s_rel = se - 2^-12*dotq ; group min + nibble bitmap
    const float inv = 1.0f / 4096.0f;
#pragma unroll
    for (int c = 0; c < 4; ++c) {
        unsigned pk[4];
#pragma unroll
        for (int r = 0; r < 4; ++r) {
            float s0 = sev[r][0] - acc[r][c][0] * inv;
            float s1 = sev[r][1] - acc[r][c][1] * inv;
            float s2 = sev[r][2] - acc[r][c][2] * inv;
            float s3 = sev[r][3] - acc[r][c][3] * inv;
            float mn = fminf(fminf(s0, s1), fminf(s2, s3));
            mn = fminf(mn, __shfl_xor(mn, 16));
            mn = fminf(mn, __shfl_xor(mn, 32));
            float t = mn + MARGIN;
            unsigned nib = (s0 <= t ? 1u : 0u) | (s1 <= t ? 2u : 0u)
                         | (s2 <= t ? 4u : 0u) | (s3 <= t ? 8u : 0u);
            nib <<= (4 * q);
            nib |= (unsigned)__shfl_xor((int)nib, 16);
            nib |= (unsigned)__shfl_xor((int)nib, 32);
            pk[r] = ((unsigned)f2h(mn)) | (nib << 16);
        }
        if (lane < 16) {
            int grow = row0 + rbase + 16 * c + m16;
            int base = (code0 + wc) >> 4;
            *(uint4*)&packed[(size_t)grow * 512 + base] =
                make_uint4(pk[0], pk[1], pk[2], pk[3]);
        }
    }
}

// ---------------------------------------------------------------------------
// Kernel 3 (fused): global min of fp16 group mins -> flagged groups ->
// candidate codes -> exact fp32 rescore (R1's bit-identical chain) -> outputs.
// ---------------------------------------------------------------------------
__global__ __launch_bounds__(256) void argmin_out_kernel(
        const float* __restrict__ lat, const float* __restrict__ emb,
        const float* __restrict__ row_sq, const float* __restrict__ emb_sq,
        const unsigned int* __restrict__ packed,
        const int* __restrict__ gold,
        float* __restrict__ out, int* __restrict__ counter) {
    __shared__ float xs[4][DIM];
    __shared__ int   s_cnt[4];
    __shared__ int   s_list[4][CAND_CAP];
    const int w    = threadIdx.x >> 6;
    const int lane = threadIdx.x & 63;
    const int row  = blockIdx.x * 4 + w;

    {
        const float4* xp = (const float4*)(lat + (size_t)row * DIM);
        ((float4*)xs[w])[lane]      = xp[lane];
        ((float4*)xs[w])[lane + 64] = xp[lane + 64];
    }
    const float sx = row_sq[row];
    const float* xw = xs[w];

    unsigned u[8];
    {
        const uint4* tb = (const uint4*)(packed + (size_t)row * 512 + lane * 8);
        uint4 v0 = tb[0], v1 = tb[1];
        u[0] = v0.x; u[1] = v0.y; u[2] = v0.z; u[3] = v0.w;
        u[4] = v1.x; u[5] = v1.y; u[6] = v1.z; u[7] = v1.w;
    }
    float tm[8];
#pragma unroll
    for (int j = 0; j < 8; ++j) tm[j] = h2f((unsigned short)(u[j] & 0xFFFFu));
    float m = tm[0];
#pragma unroll
    for (int j = 1; j < 8; ++j) m = fminf(m, tm[j]);
#pragma unroll
    for (int off = 1; off < 64; off <<= 1)
        m = fminf(m, __shfl_xor(m, off));
    const float thresh = m + (MARGIN + FLAG_SLACK);

    if (lane == 0) s_cnt[w] = 0;
    __syncthreads();
#pragma unroll
    for (int j = 0; j < 8; ++j) {
        if (tm[j] <= thresh) {
            int g = lane * 8 + j;
            unsigned bm = u[j] >> 16;
            while (bm) {
                int b = __ffs(bm) - 1;
                bm &= bm - 1;
                int pos = atomicAdd(&s_cnt[w], 1);
                if (pos < CAND_CAP) s_list[w][pos] = g * 16 + b;
            }
        }
    }
    __syncthreads();
    const int cnt = min(s_cnt[w], CAND_CAP);

    float bd = INFINITY;
    int   bi = 0x7fffffff;
    for (int base = 0; base < cnt; base += 64) {
        int ci = base + lane;
        float dvl = INFINITY;
        int   cl  = 0x7fffffff;
        if (ci < cnt) {
            int code = s_list[w][ci];
            const float* ep = emb + (size_t)code * DIM;
            float acc = 0.0f;
            for (int d = 0; d < DIM; d += 8) {
                float ev[8], xv[8];
#pragma unroll
                for (int t = 0; t < 8; ++t) { ev[t] = ep[d + t]; xv[t] = xw[d + t]; }
#pragma unroll
                for (int t = 0; t < 8; ++t) acc = fmaf(xv[t], ev[t], acc);
            }
            float a = sx + emb_sq[code];
            dvl = a - 2.0f * acc;
            cl  = code;
        }
        if (dvl < bd || (dvl == bd && cl < bi)) { bd = dvl; bi = cl; }
    }
#pragma unroll
    for (int off = 1; off < 64; off <<= 1) {
        float od = __shfl_xor(bd, off);
        int   oi = __shfl_xor(bi, off);
        if (od < bd || (od == bd && oi < bi)) { bd = od; bi = oi; }
    }
    const int idx = bi;

    const float4* e4 = (const float4*)(emb + (size_t)idx * DIM);
    float4*       q4 = (float4*)(out + (size_t)row * DIM);
    q4[lane]      = e4[lane];
    q4[lane + 64] = e4[lane + 64];

    float r = 0.0f;
    if (lane < 32) {
        const int b = lane >> 3, j = lane & 7;
        const float* ep = emb + (size_t)idx * DIM + b * 128 + j;
        const float* xp = xw + b * 128 + j;
        for (int i = 0; i < 16; ++i) {
            float dq = ep[8 * i] - xp[8 * i];
            float s  = dq * dq;
            r = (i == 0) ? s : (r + s);
        }
    }
    for (int mm = 1; mm <= 16; mm <<= 1) {
        float o = __shfl_xor(r, mm);
        r = r + o;
    }
    if (lane == 0) {
        float mean = r * (1.0f / 512.0f);
        float v    = mean + 0.25f * mean;
        out[(size_t)N_ROWS * DIM + row]          = v;
        out[(size_t)N_ROWS * DIM + N_ROWS + row] = (float)idx;
        if (gold[row] == idx) atomicAdd(counter, 1);
    }
}

__global__ void tail_kernel(const int* __restrict__ counter,
                            float* __restrict__ out) {
    if (threadIdx.x == 0 && blockIdx.x == 0) {
        const size_t off = (size_t)N_ROWS * DIM + 2 * (size_t)N_ROWS;
        out[off]     = (float)(*counter);
        out[off + 1] = (float)N_ROWS;
    }
}

// ---------------------------------------------------------------------------
// Fallback path (tiny ws): R1 fp32 dist + separate sq/out kernels.
// ---------------------------------------------------------------------------
__global__ __launch_bounds__(256) void sq_kernel(
        const float* __restrict__ lat, const float* __restrict__ emb,
        float* __restrict__ row_sq, float* __restrict__ emb_sq) {
#pragma clang fp contract(off)
    const int w    = threadIdx.x >> 6;
    const int lane = threadIdx.x & 63;
    const int half = lane >> 5;
    const int L    = lane & 31;
    const int b    = L >> 3, j = L & 7;
    const int row  = blockIdx.x * 8 + w * 2 + half;
    if (row >= N_ROWS + KCB) return;
    const float* p = (row < N_ROWS) ? (lat + (size_t)row * DIM)
                                    : (emb + (size_t)(row - N_ROWS) * DIM);
    const float* q = p + 128 * b + j;
    float a0 = q[0];
    float r  = a0 * a0;
    for (int i = 1; i < 16; ++i) {
        float a = q[8 * i];
        float s = a * a;
        r = r + s;
    }
    r = r + __shfl_xor(r, 1);
    r = r + __shfl_xor(r, 2);
    r = r + __shfl_xor(r, 4);
    r = r + __shfl_xor(r, 8);
    r = r + __shfl_xor(r, 16);
    if (L == 0) {
        if (row < N_ROWS) row_sq[row] = r;
        else              emb_sq[row - N_ROWS] = r;
    }
}

#define BM 64
#define BK 128
#define BD 32
__global__ __launch_bounds__(256) void dist_kernel(
        const float* __restrict__ lat, const float* __restrict__ emb,
        const float* __restrict__ row_sq, const float* __restrict__ emb_sq,
        int* __restrict__ enc) {
    __shared__ float xsh[BD][BM];
    __shared__ float esh[BD][BK];
    const int tid  = threadIdx.x;
    const int trow = tid >> 4;
    const int tcol = tid & 15;
    const int row0 = blockIdx.x * BM;
    float bd[4]; int bi[4];
    for (int i = 0; i < 4; ++i) { bd[i] = INFINITY; bi[i] = 0; }
    float sx[4];
    for (int i = 0; i < 4; ++i) sx[i] = row_sq[row0 + 4 * trow + i];
    for (int kt = 0; kt < KCB; kt += BK) {
        float acc[4][8] = {};
        for (int d0 = 0; d0 < DIM; d0 += BD) {
            for (int f = tid; f < BM * BD / 4; f += 256) {
                int r = f >> 3, c4 = f & 7;
                float4 v = *(const float4*)(lat + (size_t)(row0 + r) * DIM + d0 + 4 * c4);
                xsh[4 * c4 + 0][r] = v.x; xsh[4 * c4 + 1][r] = v.y;
                xsh[4 * c4 + 2][r] = v.z; xsh[4 * c4 + 3][r] = v.w;
            }
            for (int f = tid; f < BK * BD / 4; f += 256) {
                int r = f >> 3, c4 = f & 7;
                float4 v = *(const float4*)(emb + (size_t)(kt + r) * DIM + d0 + 4 * c4);
                esh[4 * c4 + 0][r] = v.x; esh[4 * c4 + 1][r] = v.y;
                esh[4 * c4 + 2][r] = v.z; esh[4 * c4 + 3][r] = v.w;
            }
            __syncthreads();
            for (int dd = 0; dd < BD; ++dd) {
                float4 xv  = *(const float4*)&xsh[dd][4 * trow];
                float4 ev0 = *(const float4*)&esh[dd][8 * tcol];
                float4 ev1 = *(const float4*)&esh[dd][8 * tcol + 4];
                float xr[4] = { xv.x, xv.y, xv.z, xv.w };
                float ec[8] = { ev0.x, ev0.y, ev0.z, ev0.w, ev1.x, ev1.y, ev1.z, ev1.w };
                for (int r = 0; r < 4; ++r)
                    for (int c = 0; c < 8; ++c)
                        acc[r][c] = fmaf(xr[r], ec[c], acc[r][c]);
            }
            __syncthreads();
        }
        for (int c = 0; c < 8; ++c) {
            int   code = kt + 8 * tcol + c;
            float se   = emb_sq[code];
            for (int r = 0; r < 4; ++r) {
                float a  = sx[r] + se;
                float dv = a - 2.0f * acc[r][c];
                if (dv < bd[r]) { bd[r] = dv; bi[r] = code; }
            }
        }
    }
    for (int off = 1; off < 16; off <<= 1) {
        for (int r = 0; r < 4; ++r) {
            float od = __shfl_xor(bd[r], off);
            int   oi = __shfl_xor(bi[r], off);
            if (od < bd[r] || (od == bd[r] && oi < bi[r])) { bd[r] = od; bi[r] = oi; }
        }
    }
    if (tcol == 0)
        for (int r = 0; r < 4; ++r)
            enc[row0 + 4 * trow + r] = bi[r];
}

__global__ void out_kernel(const float* __restrict__ lat,
                           const float* __restrict__ emb,
                           const int* __restrict__ gold,
                           const int* __restrict__ enc,
                           float* __restrict__ out,
                           int* __restrict__ counter) {
#pragma clang fp contract(off)
    const int gid  = blockIdx.x * blockDim.x + threadIdx.x;
    const int row  = gid >> 6;
    const int lane = threadIdx.x & 63;
    if (row >= N_ROWS) return;
    const int idx = enc[row];
    const float4* e4 = (const float4*)(emb + (size_t)idx * DIM);
    float4*       q4 = (float4*)(out + (size_t)row * DIM);
    q4[lane]      = e4[lane];
    q4[lane + 64] = e4[lane + 64];
    float r = 0.0f;
    if (lane < 32) {
        const int b = lane >> 3, j = lane & 7;
        const float* ep = emb + (size_t)idx * DIM + b * 128 + j;
        const float* xp = lat + (size_t)row * DIM + b * 128 + j;
        for (int i = 0; i < 16; ++i) {
            float dq = ep[8 * i] - xp[8 * i];
            float s  = dq * dq;
            r = (i == 0) ? s : (r + s);
        }
    }
    for (int m = 1; m <= 16; m <<= 1) {
        float o = __shfl_xor(r, m);
        r = r + o;
    }
    if (lane == 0) {
        float mean = r * (1.0f / 512.0f);
        float v    = mean + 0.25f * mean;
        out[(size_t)N_ROWS * DIM + row]          = v;
        out[(size_t)N_ROWS * DIM + N_ROWS + row] = (float)idx;
        if (gold[row] == idx) atomicAdd(counter, 1);
    }
}

// ---------------------------------------------------------------------------
extern "C" void kernel_launch(void* const* d_in, const int* in_sizes, int n_in,
                              void* d_out, int out_size, void* d_ws, size_t ws_size,
                              hipStream_t stream) {
    (void)in_sizes; (void)n_in; (void)out_size;
    const int*   gold = (const int*)d_in[0];
    const float* lat  = (const float*)d_in[1];
    const float* emb  = (const float*)d_in[3];
    float* out = (float*)d_out;

    const size_t SZ_LATQ = (size_t)N_ROWS * DIM;         // 16 MB
    const size_t SZ_EMBQ = (size_t)KCB * DIM;            //  4 MB
    const size_t SZ_PK   = (size_t)N_ROWS * 512 * 4;     // 64 MB
    const size_t SZ_SMALL = (size_t)N_ROWS * 4 + (size_t)KCB * 4 + 256;
    const size_t NEEDED = SZ_LATQ + SZ_EMBQ + SZ_PK + SZ_SMALL;

    if (ws_size >= NEEDED) {
        unsigned char* w8 = (unsigned char*)d_ws;
        unsigned char* latq    = w8;
        unsigned char* embq    = w8 + SZ_LATQ;
        unsigned int*  packed  = (unsigned int*)(w8 + SZ_LATQ + SZ_EMBQ);
        float*         row_sq  = (float*)(w8 + SZ_LATQ + SZ_EMBQ + SZ_PK);
        float*         emb_sq  = row_sq + N_ROWS;
        int*           counter = (int*)(emb_sq + KCB);

        const int pre_blocks = SQ_BLOCKS + (N_ROWS + KCB) * (DIM / 8) / 256;
        pre_kernel<<<pre_blocks, 256, 0, stream>>>(
            lat, emb, row_sq, emb_sq, latq, embq, counter);
        dim3 ggrid(N_ROWS / 128, KCB / 128);
        gemm_kernel<<<ggrid, 256, 0, stream>>>(latq, embq, emb_sq, packed);
        argmin_out_kernel<<<N_ROWS / 4, 256, 0, stream>>>(
            lat, emb, row_sq, emb_sq, packed, gold, out, counter);
        tail_kernel<<<1, 64, 0, stream>>>(counter, out);
    } else {
        float* row_sq  = (float*)d_ws;
        float* emb_sq  = row_sq + N_ROWS;
        int*   enc     = (int*)(emb_sq + KCB);
        int*   counter = enc + N_ROWS;
        hipMemsetAsync(counter, 0, sizeof(int), stream);
        sq_kernel<<<(N_ROWS + KCB) / 8, 256, 0, stream>>>(lat, emb, row_sq, emb_sq);
        dist_kernel<<<N_ROWS / BM, 256, 0, stream>>>(lat, emb, row_sq, emb_sq, enc);
        out_kernel<<<N_ROWS / 4, 256, 0, stream>>>(lat, emb, gold, enc, out, counter);
        tail_kernel<<<1, 64, 0, stream>>>(counter, out);
    }
}